// Round 12
// baseline (290.972 us; speedup 1.0000x reference)
//
#include <hip/hip_runtime.h>
#include <hip/hip_bf16.h>

#define B_    256
#define L_    512
#define DV    21
#define NROW  5376       // B_*DV
#define NP    32
#define PP    16
#define PRED_ 96

// ---------------- workspace layout (float indices) ----------------
static const size_t OFF_XT    = 0;          // 5376x512 f32
static const size_t OFF_ZA    = 2752512;    // z_dct -> z (DCT chain)
static const size_t OFF_Z1    = 5505024;
static const size_t OFF_ZCP   = 8257536;    // zc_pre -> z2f (in-place)
static const size_t OFF_D2    = 11010048;   // D2hi bf16 (131072 f) + D2lo bf16 (131072 f)
static const size_t OFF_D3    = 11272192;   // D3h bf16 (131072 f)
static const size_t OFF_TN    = 11583488;   // 32x16x16
static const size_t OFF_TB    = 11591680;   // 32x16
static const size_t OFF_C     = 11592192;   // 96 (pad 128)
static const size_t OFF_EN    = 11592320;   // 5376
static const size_t OFF_NORM  = 11597696;
static const size_t OFF_ATT   = 11603072;
static const size_t OFF_ATT1  = 11608448;   // dvec (512)
static const size_t OFF_STAT  = 11613824;   // [200],[201]=quantile order stats
static const size_t OFF_ABP   = 11614144;
static const size_t OFF_ABDEP = 11614208;
static const size_t OFF_FLAG  = 11614272;   // int mode flag (1=f32 inputs, 0=bf16)
static const size_t OFF_STG   = 11614336;   // staged f32 weights (854480) -> ends 12468816
static const size_t OFF_T     = 12468816;   // t / z2 buffer (2752512)
static const size_t OFF_PARTP = 15221328;   // patch stats partials 64x1344
static const size_t OFF_PARTD = 15307344;   // depth stats partials 64x1344
static const size_t OFF_EPART = 15393360;   // energy partials 5376x8
static const size_t OFF_PARTM = 15436368;   // maskgelu BN partials 42x256
static const size_t OFF_BCAT  = 15447120;   // BcatTh bf16 256x512 (65536 floats)
static const size_t OFF_PM    = 15512656;   // foldM partials 8x49152
static const size_t OFF_PC    = 15905872;   // foldC partials 256x96
// total ~15.93M floats = 63.7 MB (ws = 256 MiB)

// staged-weight offsets (relative to OFF_STG)
static const int S_WDCT=0, S_BDCT=24, S_WE=48, S_BE=4144, S_WL=4400, S_BL=790832,
  S_WD=790928, S_BDRES=795024, S_WDC=795040, S_BDC=795552, S_WDC1=795584, S_BDC1=795680,
  S_GD=795712, S_BDN=795736, S_GP=795760, S_BP=795792, S_GDEP=795824, S_BDEP=795856,
  S_THR=795888, S_WM1=795892, S_BM1=845044, S_WM2=845140, S_BM2=854356,
  S_ADWW=854452, S_ADWB=854460, S_ACW=854464, S_ACB=854468, S_AG=854472, S_AB2=854476;

struct Ptrs { const void* p[30]; };

typedef __attribute__((ext_vector_type(8))) short bf16x8;
typedef __attribute__((ext_vector_type(4))) short bf16x4;
typedef __attribute__((ext_vector_type(4))) float f32x4;

__device__ __forceinline__ float bf2f(unsigned short h){
  unsigned u = ((unsigned)h) << 16;
  return __uint_as_float(u);
}
__device__ __forceinline__ short f2b(float f){   // RNE f32 -> bf16
  unsigned u = __float_as_uint(f);
  u = (u + 0x7FFFu + ((u >> 16) & 1u)) >> 16;
  return (short)u;
}
__device__ __forceinline__ float gelu_f(float x){ return 0.5f*x*(1.0f+erff(x*0.70710678118654752440f)); }

#define RD(P,I) (mode ? ((const float*)(P))[(I)] : bf2f(((const unsigned short*)(P))[(I)]))

// ================= setup: stage + transpose + dctmats/dvec + zero + folds (partials) =================
__global__ __launch_bounds__(256) void k_setup(Ptrs ptrs, float* __restrict__ W,
    float* __restrict__ xt, unsigned short* __restrict__ D2h, unsigned short* __restrict__ D2l,
    unsigned short* __restrict__ D3h, float* __restrict__ dvec,
    float* __restrict__ PM, float* __restrict__ PC,
    float* __restrict__ Tn, float* __restrict__ tb){
  int b = blockIdx.x, tid = threadIdx.x;
  int mode = (((const unsigned*)ptrs.p[13])[0] == 0x3F800000u) ? 1 : 0;
  float* S = W + OFF_STG;
  if (b < 3338){
    const int cnt[29] = {21,21,4096,256,786432,96,4096,16,512,32,96,32,21,21,32,32,32,32,1,49152,96,9216,96,5,1,1,1,1,1};
    const int off[29] = {S_WDCT,S_BDCT,S_WE,S_BE,S_WL,S_BL,S_WD,S_BDRES,S_WDC,S_BDC,S_WDC1,S_BDC1,
                         S_GD,S_BDN,S_GP,S_BP,S_GDEP,S_BDEP,S_THR,S_WM1,S_BM1,S_WM2,S_BM2,
                         S_ADWW,S_ADWB,S_ACW,S_ACB,S_AG,S_AB2};
    int gid = b*256 + tid;
    int a = -1, loc = 0, base = 0;
    #pragma unroll
    for (int i = 0; i < 29; i++){
      if (a < 0 && gid < base + cnt[i]){ a = i; loc = gid - base; }
      base += cnt[i];
    }
    if (a < 0) return;
    S[off[a] + loc] = RD(ptrs.p[a+1], loc);
  } else if (b < 4362){
    __shared__ float xs[128*DV];
    int b2 = b - 3338;
    int bb = b2 >> 2, ch = b2 & 3;
    int l0 = ch*128;
    size_t base = (size_t)bb*(L_*DV) + (size_t)l0*DV;
    for (int i = tid; i < 128*DV; i += 256) xs[i] = RD(ptrs.p[0], base + i);
    __syncthreads();
    for (int i = tid; i < 128*DV; i += 256){
      int d = i >> 7, l = i & 127;
      xt[((size_t)bb*DV + d)*512 + l0 + l] = xs[l*DV + d];
    }
  } else if (b < 5386){
    int i = (b - 4362)*256 + tid;
    int kk = i >> 9, m = i & 511;
    const float PIo = 3.14159265358979323846f / 1024.0f;
    int a = ((2*m+1)*kk) & 2047;
    float v = 2.0f * cosf(PIo * (float)a);
    short hi = f2b(v);
    D2h[i] = (unsigned short)hi;
    D2l[i] = (unsigned short)f2b(v - bf2f((unsigned short)hi));
    int a2 = ((2*kk+1)*m) & 2047;
    float w0 = (m==0) ? 0.5f : 1.0f;
    D3h[i] = (unsigned short)f2b(cosf(PIo * (float)a2) * w0 * (1.0f/512.0f));
    if (i < 512){
      const float rs = 22.627416997969522f;
      float s = 0.f;
      #pragma unroll
      for (int k5 = 0; k5 < 5; k5++){
        float awk = RD(ptrs.p[24], k5);
        float sk = ((k5 == 0) ? 0.5f : 0.70710678118654752440f) / rs;
        int a5 = ((2*i+1)*k5) & 2047;
        s += 2.0f * cosf(PIo * (float)a5) * sk * awk;
      }
      dvec[i] = s;
    }
  } else if (b == 5386){
    W[OFF_STAT + tid] = 0.0f;
    if (tid == 0) *(int*)(W + OFF_FLAG) = mode;
  } else if (b < 6923){
    int bb2 = b - 5387;
    int y = bb2 / 192, xb = bb2 - y*192;
    int gid = xb*256 + tid;
    int l = gid/96, p = gid - l*96;
    int n = l>>4, q = l&15;
    int j0 = y*32;
    float acc = 0.f;
    #pragma unroll 8
    for (int j = j0; j < j0+32; j++)
      acc += RD(ptrs.p[3], q*256+j) * RD(ptrs.p[5], (size_t)(n*256+j)*96 + p);
    PM[(size_t)y*49152 + gid] = acc;
  } else if (b < 7051){
    int blkC = b - 6923;
    int rp = tid >> 7, p = tid & 127;
    if (p >= 96) return;
    float acc = 0.f;
    int J0 = blkC*64;
    for (int j = 0; j < 64; j += 2){
      int J = J0 + j + rp;
      acc += RD(ptrs.p[4], J & 255) * RD(ptrs.p[5], (size_t)J*96 + p);
    }
    if (blkC == 0 && rp == 0) acc += RD(ptrs.p[6], p);
    PC[(blkC*2 + rp)*96 + p] = acc;
  } else {
    __shared__ float WeS[4096];
    __shared__ float WdS[4096];
    __shared__ float wdcS[16];
    __shared__ float beS[256];
    __shared__ float bdresS[16];
    int n = b - 7051;
    for (int i = tid; i < 4096; i += 256){ WeS[i] = RD(ptrs.p[3], i); WdS[i] = RD(ptrs.p[7], i); }
    beS[tid] = RD(ptrs.p[4], tid);
    if (tid < 16){ wdcS[tid] = RD(ptrs.p[9], n*16 + tid); bdresS[tid] = RD(ptrs.p[8], tid); }
    __syncthreads();
    int q2 = tid>>4, q = tid&15;
    float R = 0.f;
    for (int j = 0; j < 256; j++) R += WeS[q2*256+j] * WdS[j*16+q];
    float G = 0.f;
    #pragma unroll
    for (int p = 0; p < 16; p++) G += WeS[q2*256 + q*16 + p] * wdcS[p];
    Tn[n*256 + q2*16 + q] = R + G;
    if (tid < 16){
      float rb = bdresS[tid];
      for (int j = 0; j < 256; j++) rb += beS[j] * WdS[j*16+tid];
      float gb = RD(ptrs.p[10], n);
      #pragma unroll
      for (int p = 0; p < 16; p++) gb += beS[tid*16+p] * wdcS[p];
      tb[n*16+tid] = rb + gb;
    }
  }
}

// ================= mega: DCT-GEMM || patch || bcat(+M reduce) || c reduce =================
__global__ __launch_bounds__(256) void k_mega(
    const float* __restrict__ xt, const unsigned short* __restrict__ Bh16,
    const unsigned short* __restrict__ Bl16, float* __restrict__ C,
    float* __restrict__ e_part, const int* __restrict__ flag,
    const float* __restrict__ Tn, const float* __restrict__ tb,
    float* __restrict__ t, float* __restrict__ partP,
    const float* __restrict__ S, const float* __restrict__ PM,
    const float* __restrict__ PC, float* __restrict__ cb, unsigned short* __restrict__ Bt){
  int b = blockIdx.x, tid = threadIdx.x;
  if (b < 672){
    __shared__ short Ahi[64*40];
    __shared__ short Alo[64*40];
    __shared__ short Bhi[64*40];
    __shared__ short Blo[64*40];
    int mode = *flag;
    int bx = b & 7, by = b >> 3;
    int rowBase = by*64, colBase = bx*64;
    int srow = tid>>2, seg = tid&3;
    int r = rowBase + srow;
    int wave = tid>>6, lane = tid&63;
    int m = lane&15, quad = lane>>4;
    f32x4 acc[4] = {};
    for (int k0 = 0; k0 < 512; k0 += 32){
      float4 a0 = *(const float4*)(xt + (size_t)r*512 + k0 + seg*8);
      float4 a1 = *(const float4*)(xt + (size_t)r*512 + k0 + seg*8 + 4);
      bf16x8 ah;
      float av[8] = {a0.x,a0.y,a0.z,a0.w,a1.x,a1.y,a1.z,a1.w};
      #pragma unroll
      for (int j = 0; j < 8; j++) ah[j] = f2b(av[j]);
      *(bf16x8*)(Ahi + srow*40 + seg*8) = ah;
      if (mode){
        bf16x8 al;
        #pragma unroll
        for (int j = 0; j < 8; j++) al[j] = f2b(av[j] - bf2f((unsigned short)ah[j]));
        *(bf16x8*)(Alo + srow*40 + seg*8) = al;
      }
      *(bf16x8*)(Bhi + srow*40 + seg*8) = *(const bf16x8*)(Bh16 + (size_t)(colBase+srow)*512 + k0 + seg*8);
      *(bf16x8*)(Blo + srow*40 + seg*8) = *(const bf16x8*)(Bl16 + (size_t)(colBase+srow)*512 + k0 + seg*8);
      __syncthreads();
      bf16x8 afh = *(bf16x8*)(Ahi + (wave*16 + m)*40 + quad*8);
      #pragma unroll
      for (int tt = 0; tt < 4; tt++){
        bf16x8 bfh = *(bf16x8*)(Bhi + (tt*16 + m)*40 + quad*8);
        bf16x8 bfl = *(bf16x8*)(Blo + (tt*16 + m)*40 + quad*8);
        acc[tt] = __builtin_amdgcn_mfma_f32_16x16x32_bf16(afh, bfh, acc[tt], 0, 0, 0);
        acc[tt] = __builtin_amdgcn_mfma_f32_16x16x32_bf16(afh, bfl, acc[tt], 0, 0, 0);
      }
      if (mode){
        bf16x8 afl = *(bf16x8*)(Alo + (wave*16 + m)*40 + quad*8);
        #pragma unroll
        for (int tt = 0; tt < 4; tt++){
          bf16x8 bfh = *(bf16x8*)(Bhi + (tt*16 + m)*40 + quad*8);
          bf16x8 bfl = *(bf16x8*)(Blo + (tt*16 + m)*40 + quad*8);
          acc[tt] = __builtin_amdgcn_mfma_f32_16x16x32_bf16(afl, bfh, acc[tt], 0, 0, 0);
          acc[tt] = __builtin_amdgcn_mfma_f32_16x16x32_bf16(afl, bfl, acc[tt], 0, 0, 0);
        }
      }
      __syncthreads();
    }
    float es[4] = {};
    #pragma unroll
    for (int tt = 0; tt < 4; tt++){
      #pragma unroll
      for (int i = 0; i < 4; i++){
        int rr = rowBase + wave*16 + quad*4 + i;
        int cc = colBase + tt*16 + m;
        float v = acc[tt][i];
        C[(size_t)rr*512 + cc] = v;
        es[i] += v*v;
      }
    }
    #pragma unroll
    for (int off = 1; off < 16; off <<= 1){
      #pragma unroll
      for (int i = 0; i < 4; i++) es[i] += __shfl_xor(es[i], off);
    }
    if (m == 0){
      #pragma unroll
      for (int i = 0; i < 4; i++){
        int rr = rowBase + wave*16 + quad*4 + i;
        e_part[rr*8 + bx] = es[i];
      }
    }
  } else if (b < 2016){
    int blk = b - 672;
    int n0 = tid >> 4, qq = tid & 15;
    int n1 = n0 + 16;
    float T0[16], T1[16];
    #pragma unroll
    for (int q2 = 0; q2 < 16; q2++){
      T0[q2] = Tn[n0*256 + q2*16 + qq];
      T1[q2] = Tn[n1*256 + q2*16 + qq];
    }
    float tb0 = tb[n0*16 + qq], tb1 = tb[n1*16 + qq];
    float s0 = 0.f, q0 = 0.f, s1 = 0.f, q1 = 0.f;
    #pragma unroll
    for (int rr = 0; rr < 4; rr++){
      int r = blk*4 + rr;
      float x0 = xt[(size_t)r*512 + tid];
      float x1 = xt[(size_t)r*512 + tid + 256];
      float a0 = tb0, a1 = tb1;
      #pragma unroll
      for (int q2 = 0; q2 < 16; q2++){
        a0 += __shfl(x0, q2, 16) * T0[q2];
        a1 += __shfl(x1, q2, 16) * T1[q2];
      }
      t[(size_t)r*512 + tid] = a0;       s0 += a0; q0 += a0*a0;
      t[(size_t)r*512 + tid + 256] = a1; s1 += a1; q1 += a1*a1;
    }
    #pragma unroll
    for (int off = 1; off < 16; off <<= 1){
      s0 += __shfl_xor(s0, off); q0 += __shfl_xor(q0, off);
      s1 += __shfl_xor(s1, off); q1 += __shfl_xor(q1, off);
    }
    if (qq == 0){
      partP[(2*n0)*1344 + blk] = s0; partP[(2*n0+1)*1344 + blk] = q0;
      partP[(2*n1)*1344 + blk] = s1; partP[(2*n1+1)*1344 + blk] = q1;
    }
  } else if (b < 2528){
    int i = (b - 2016)*256 + tid;
    int cc = i >> 9, mm = i & 511;
    float v = 0.f;
    if (cc < 96) v = S[S_WM1 + mm*96 + cc];
    else if (cc >= 128 && cc < 224){
      int idx = mm*96 + (cc - 128);
      #pragma unroll
      for (int y = 0; y < 8; y++) v += PM[(size_t)y*49152 + idx];
    }
    Bt[i] = (unsigned short)f2b(v);
  } else {
    if (tid < 96){
      float a = 0.f;
      for (int j = 0; j < 256; j++) a += PC[j*96 + tid];
      cb[tid] = a;
    }
  }
}

// ---------------- shared device: BN finalize from partials ----------------
__device__ __forceinline__ void dev_bnfin(const float* part, int P, const float* g,
    const float* bb, float count, float* ab, int c, int tid){
  const float* ps = part + (size_t)(2*c)*P;
  const float* pq = part + (size_t)(2*c+1)*P;
  float s = 0.f, s2 = 0.f;
  for (int i = tid; i < P; i += 256){ s += ps[i]; s2 += pq[i]; }
  for (int off = 32; off; off >>= 1){ s += __shfl_down(s, off); s2 += __shfl_down(s2, off); }
  __shared__ float ws[4][2];
  if ((tid & 63) == 0){ ws[tid>>6][0] = s; ws[tid>>6][1] = s2; }
  __syncthreads();
  if (tid == 0){
    float S1 = ws[0][0]+ws[1][0]+ws[2][0]+ws[3][0];
    float S2 = ws[0][1]+ws[1][1]+ws[2][1]+ws[3][1];
    float mean = S1 / count;
    float var  = S2 / count - mean*mean;
    float al = g[c] * rsqrtf(var + 1e-5f);
    float be = bb[c] - mean * al;
    ab[2*c] = al; ab[2*c+1] = be;
  }
}

// ================= mid1: block0 = energy-reduce + median ; blocks 1..32 = patch BN fin =================
__global__ __launch_bounds__(256) void k_mid1(const float* __restrict__ e_part,
    float* __restrict__ en, float* __restrict__ norm,
    const float* __restrict__ partP, const float* __restrict__ S, float* __restrict__ abp){
  int b = blockIdx.x, tid = threadIdx.x;
  if (b == 0){
    for (int r = tid; r < NROW; r += 256){
      float s = 0.f;
      #pragma unroll
      for (int j = 0; j < 8; j++) s += e_part[r*8 + j];
      en[r] = s;
    }
    __syncthreads();
    int bb = tid;
    float v[DV];
    for (int d = 0; d < DV; d++) v[d] = en[bb*DV + d];
    float med = 0.f;
    for (int i = 0; i < DV; i++){
      int rk = 0;
      for (int j = 0; j < DV; j++) rk += (v[j] < v[i]) || (v[j] == v[i] && j < i);
      if (rk == 10) med = v[i];
    }
    float den = med + 1e-6f;
    for (int d = 0; d < DV; d++) norm[bb*DV + d] = v[d] / den;
  } else {
    dev_bnfin(partP, 1344, S + S_GP, S + S_BP, 86016.0f, abp, b - 1, tid);
  }
}

// ================= mid2: blocks 0..335 = rank ; 336..1679 = z2/conv3 =================
__global__ __launch_bounds__(256) void k_mid2(const float* __restrict__ norm,
    const float* __restrict__ S, float* __restrict__ stat,
    float* __restrict__ t, float* __restrict__ zcp,
    const float* __restrict__ abp, float* __restrict__ partD){
  int b = blockIdx.x, tid = threadIdx.x;
  if (b < 336){
    int cand = tid >> 4, part = tid & 15;
    int idx = b*16 + cand;
    float val = norm[idx];
    int cnt = 0;
    int j0 = part*336;
    for (int j = j0; j < j0 + 336; ++j){
      float v = norm[j];
      cnt += (v < val) || (v == val && j < idx);
    }
    __shared__ int sc[16][17];
    sc[cand][part] = cnt;
    __syncthreads();
    if (part == 0){
      int rank = 0;
      #pragma unroll
      for (int i = 0; i < 16; i++) rank += sc[cand][i];
      float q = S[S_THR];
      float pos = q * 5375.0f;
      int i0 = (int)floorf(pos);
      int i1 = (i0 + 1 > 5375) ? 5375 : i0 + 1;
      if (rank == i0) stat[200] = val;
      if (rank == i1) stat[201] = val;
    }
  } else {
    int blk = b - 336;
    const float* wdc1 = S + S_WDC1;
    const float* bdc1 = S + S_BDC1;
    int n0 = tid >> 4, qq = tid & 15;
    int n1 = n0 + 16;
    float al0 = abp[2*n0], be0 = abp[2*n0+1], al1 = abp[2*n1], be1 = abp[2*n1+1];
    float w00 = wdc1[n0*3], w01 = wdc1[n0*3+1], w02 = wdc1[n0*3+2], bb0 = bdc1[n0];
    float w10 = wdc1[n1*3], w11 = wdc1[n1*3+1], w12 = wdc1[n1*3+2], bb1 = bdc1[n1];
    float s0 = 0.f, q0 = 0.f, s1 = 0.f, q1 = 0.f;
    #pragma unroll
    for (int rr = 0; rr < 4; rr++){
      int r = blk*4 + rr;
      float v0 = t[(size_t)r*512 + tid];
      float v1 = t[(size_t)r*512 + tid + 256];
      float z0  = gelu_f(al0*v0 + be0);
      float z1v = gelu_f(al1*v1 + be1);
      float l0 = __shfl_up(z0, 1, 16);    if (qq == 0)  l0 = 0.f;
      float r0 = __shfl_down(z0, 1, 16);  if (qq == 15) r0 = 0.f;
      float l1 = __shfl_up(z1v, 1, 16);   if (qq == 0)  l1 = 0.f;
      float r1 = __shfl_down(z1v, 1, 16); if (qq == 15) r1 = 0.f;
      float cv0 = w00*l0 + w01*z0  + w02*r0 + bb0;
      float cv1 = w10*l1 + w11*z1v + w12*r1 + bb1;
      zcp[(size_t)r*512 + tid] = cv0;       t[(size_t)r*512 + tid] = z0;
      zcp[(size_t)r*512 + tid + 256] = cv1; t[(size_t)r*512 + tid + 256] = z1v;
      s0 += cv0; q0 += cv0*cv0; s1 += cv1; q1 += cv1*cv1;
    }
    #pragma unroll
    for (int off = 1; off < 16; off <<= 1){
      s0 += __shfl_xor(s0, off); q0 += __shfl_xor(q0, off);
      s1 += __shfl_xor(s1, off); q1 += __shfl_xor(q1, off);
    }
    if (qq == 0){
      partD[(2*n0)*1344 + blk] = s0; partD[(2*n0+1)*1344 + blk] = q0;
      partD[(2*n1)*1344 + blk] = s1; partD[(2*n1+1)*1344 + blk] = q1;
    }
  }
}

// ================= mid3: blocks 0..5375 = maskgelu ; 5376..5407 = depth BN fin =================
__global__ __launch_bounds__(256) void k_mid3(float* __restrict__ zA, const float* __restrict__ norm,
    const float* __restrict__ stat, const float* __restrict__ S,
    float* __restrict__ partM, const float* __restrict__ partD, float* __restrict__ abdep){
  int b = blockIdx.x, tid = threadIdx.x;
  if (b < NROW){
    int r = b;
    int d = r % DV, brow = r / DV;
    float q = S[S_THR];
    float pos = q * 5375.0f; float f = pos - floorf(pos);
    float thr = stat[200] + (stat[201] - stat[200]) * f;
    float mask = norm[r] > thr ? 1.0f : 0.0f;
    float w = S[S_WDCT + d], bb = S[S_BDCT + d];
    float s = 0.f, s2 = 0.f;
    for (int i = tid; i < 512; i += 256){
      float v = zA[(size_t)r*512 + i] * mask * w + bb;
      float g = gelu_f(v);
      zA[(size_t)r*512 + i] = g;
      s += g; s2 += g*g;
    }
    for (int off = 32; off; off >>= 1){ s += __shfl_down(s, off); s2 += __shfl_down(s2, off); }
    __shared__ float wsum[4][2];
    int wv = tid >> 6;
    if ((tid & 63) == 0){ wsum[wv][0] = s; wsum[wv][1] = s2; }
    __syncthreads();
    if (tid == 0){
      float SS  = wsum[0][0]+wsum[1][0]+wsum[2][0]+wsum[3][0];
      float SS2 = wsum[0][1]+wsum[1][1]+wsum[2][1]+wsum[3][1];
      partM[(2*d)*256 + brow] = SS;
      partM[(2*d+1)*256 + brow] = SS2;
    }
  } else {
    dev_bnfin(partD, 1344, S + S_GDEP, S + S_BDEP, 86016.0f, abdep, b - NROW, tid);
  }
}

// ================= gemm1: idct MFMA GEMM with in-block dct-BN finalize =================
__global__ __launch_bounds__(256) void k_gemm1(
    const float* __restrict__ A, const unsigned short* __restrict__ Bg,
    float* __restrict__ C, const float* __restrict__ partM, const float* __restrict__ xt,
    const float* __restrict__ S){
  __shared__ short Ah[64*40];
  __shared__ short Bh[64*40];
  __shared__ float redS[84];
  __shared__ float abdS[42];
  int tid = threadIdx.x;
  if (tid < 84){
    int s = tid >> 1, h = tid & 1;
    const float* ps = partM + (size_t)s*256 + h*128;
    float a = 0.f;
    #pragma unroll 16
    for (int i = 0; i < 128; i++) a += ps[i];
    redS[tid] = a;
  }
  __syncthreads();
  if (tid < DV){
    float S1 = redS[(2*tid)*2] + redS[(2*tid)*2+1];
    float S2 = redS[(2*tid+1)*2] + redS[(2*tid+1)*2+1];
    float mean = S1 / 131072.0f;
    float var  = S2 / 131072.0f - mean*mean;
    float al = S[S_GD + tid] * rsqrtf(var + 1e-5f);
    abdS[2*tid] = al;
    abdS[2*tid+1] = S[S_BDN + tid] - mean * al;
  }
  __syncthreads();
  int rowBase = blockIdx.y*64, colBase = blockIdx.x*64;
  int srow = tid>>2, seg = tid&3;
  int r = rowBase + srow;
  int d0 = r % DV;
  float alpha = abdS[2*d0], beta = abdS[2*d0+1];
  int wave = tid>>6, lane = tid&63;
  int m = lane&15, quad = lane>>4;
  f32x4 acc[4] = {};
  for (int k0 = 0; k0 < 512; k0 += 32){
    float4 a0 = *(const float4*)(A + (size_t)r*512 + k0 + seg*8);
    float4 a1 = *(const float4*)(A + (size_t)r*512 + k0 + seg*8 + 4);
    a0.x = alpha*a0.x+beta; a0.y = alpha*a0.y+beta; a0.z = alpha*a0.z+beta; a0.w = alpha*a0.w+beta;
    a1.x = alpha*a1.x+beta; a1.y = alpha*a1.y+beta; a1.z = alpha*a1.z+beta; a1.w = alpha*a1.w+beta;
    bf16x8 av;
    av[0]=f2b(a0.x); av[1]=f2b(a0.y); av[2]=f2b(a0.z); av[3]=f2b(a0.w);
    av[4]=f2b(a1.x); av[5]=f2b(a1.y); av[6]=f2b(a1.z); av[7]=f2b(a1.w);
    *(bf16x8*)(Ah + srow*40 + seg*8) = av;
    bf16x8 bv = *(const bf16x8*)(Bg + (size_t)(colBase+srow)*512 + k0 + seg*8);
    *(bf16x8*)(Bh + srow*40 + seg*8) = bv;
    __syncthreads();
    bf16x8 af = *(bf16x8*)(Ah + (wave*16 + m)*40 + quad*8);
    #pragma unroll
    for (int t = 0; t < 4; t++){
      bf16x8 bf = *(bf16x8*)(Bh + (t*16 + m)*40 + quad*8);
      acc[t] = __builtin_amdgcn_mfma_f32_16x16x32_bf16(af, bf, acc[t], 0, 0, 0);
    }
    __syncthreads();
  }
  #pragma unroll
  for (int t = 0; t < 4; t++){
    #pragma unroll
    for (int i = 0; i < 4; i++){
      int rr = rowBase + wave*16 + quad*4 + i;
      int cc = colBase + t*16 + m;
      int d = rr % DV;
      float v = acc[t][i] + xt[(size_t)rr*512 + cc]*S[S_WDCT + d] + S[S_BDCT + d];
      C[(size_t)rr*512 + cc] = v;
    }
  }
}

// ================= z2f (in-place over zcp) fused with att dot product =================
__global__ __launch_bounds__(256) void k_z2fatt(float* __restrict__ zcp, const float* __restrict__ z2,
    const float* __restrict__ ab, const float* __restrict__ z1,
    const float* __restrict__ dvec, float* __restrict__ att){
  int r = blockIdx.x, tid = threadIdx.x;
  size_t base = (size_t)r*512;
  float s = 0.f;
  #pragma unroll
  for (int h = 0; h < 2; h++){
    int idx = tid + h*256;
    int n = (idx >> 4) & 31;
    float v = gelu_f(ab[2*n]*zcp[base+idx] + ab[2*n+1]) + z2[base+idx];
    zcp[base+idx] = v;
    s += z1[base+idx] * v * dvec[idx];
  }
  for (int off = 32; off; off >>= 1) s += __shfl_down(s, off);
  __shared__ float ws[4];
  if ((tid & 63) == 0) ws[tid>>6] = s;
  __syncthreads();
  if (tid == 0) att[r] = ws[0]+ws[1]+ws[2]+ws[3];
}

// ================= gemm_out: attfin + MLP/zres GEMM + Wm2 epilogue -> d_out =================
// 336 blocks x 16 rows x 256 cols. waves 0,1: A'=att1*z1+(1-att1)*zcp (cols 0..127);
// waves 2,3: A'=xt (cols 128..255). Wm2 read through L1/L2 (not LDS). ~40KB LDS -> 4 wg/CU.
__global__ __launch_bounds__(256) void k_gemm_out(
    const float* __restrict__ z1, const float* __restrict__ zcp, const float* __restrict__ xt,
    const unsigned short* __restrict__ Bg, const float* __restrict__ att,
    const float* __restrict__ cb, const float* __restrict__ S,
    void* __restrict__ outv, const int* __restrict__ flag){
  __shared__ short Amix[16*40];
  __shared__ short Axt[16*40];
  __shared__ short Bst[256*40];
  __shared__ float Hs[16*260];
  __shared__ float att1S[16];
  __shared__ float asum[2];
  __shared__ float ws[4][2];
  int bb = blockIdx.x, tid = threadIdx.x;
  int r0 = bb*16;
  // att global mean/var (identical order in every block -> deterministic)
  {
    float s = 0.f, s2 = 0.f;
    for (int i = tid; i < NROW; i += 256){ float a = att[i]; s += a; s2 += a*a; }
    for (int off = 32; off; off >>= 1){ s += __shfl_down(s, off); s2 += __shfl_down(s2, off); }
    if ((tid & 63) == 0){ ws[tid>>6][0] = s; ws[tid>>6][1] = s2; }
    __syncthreads();
    if (tid == 0){
      asum[0] = ws[0][0]+ws[1][0]+ws[2][0]+ws[3][0];
      asum[1] = ws[0][1]+ws[1][1]+ws[2][1]+ws[3][1];
    }
    __syncthreads();
  }
  if (tid < 16){
    int r = r0 + tid; int b2 = r / DV, d = r - b2*DV;
    float mean = asum[0] / 5376.0f;
    float var  = asum[1] / 5376.0f - mean*mean;
    float al = S[S_AG] * rsqrtf(var + 1e-5f);
    float bbx = S[S_AB2];
    float cw = S[S_ACW], cb2 = S[S_ACB];
    float v[DV]; float mx = -1e30f;
    for (int dd = 0; dd < DV; dd++){
      float a = att[b2*DV + dd];
      a = gelu_f(al*(a - mean) + bbx);
      a = a*cw + cb2;
      v[dd] = a; mx = fmaxf(mx, a);
    }
    float ss = 0.f;
    for (int dd = 0; dd < DV; dd++) ss += expf(v[dd] - mx);
    att1S[tid] = expf(v[d] - mx) / ss;
  }
  __syncthreads();
  // GEMM: 16 rows x 256 cols, K=512
  int wave = tid>>6, lane = tid&63;
  int m = lane&15, quad = lane>>4;
  f32x4 acc[4] = {};
  for (int k0 = 0; k0 < 512; k0 += 32){
    // A tiles: threads < 128 stage 16 rows x 32 k (4 elems each)
    if (tid < 128){
      int srow = tid >> 3, seg = tid & 7;
      int r = r0 + srow;
      float a1r = att1S[srow];
      float4 zf = *(const float4*)(z1  + (size_t)r*512 + k0 + seg*4);
      float4 cf = *(const float4*)(zcp + (size_t)r*512 + k0 + seg*4);
      float om = 1.0f - a1r;
      bf16x4 mv;
      mv[0] = f2b(a1r*zf.x + om*cf.x); mv[1] = f2b(a1r*zf.y + om*cf.y);
      mv[2] = f2b(a1r*zf.z + om*cf.z); mv[3] = f2b(a1r*zf.w + om*cf.w);
      *(bf16x4*)(Amix + srow*40 + seg*4) = mv;
      float4 xf = *(const float4*)(xt + (size_t)r*512 + k0 + seg*4);
      bf16x4 xv;
      xv[0] = f2b(xf.x); xv[1] = f2b(xf.y); xv[2] = f2b(xf.z); xv[3] = f2b(xf.w);
      *(bf16x4*)(Axt + srow*40 + seg*4) = xv;
    }
    // B tiles: 256 cols x 32 k
    #pragma unroll
    for (int cg = 0; cg < 4; cg++){
      int col = cg*64 + (tid>>2);
      *(bf16x8*)(Bst + col*40 + (tid&3)*8) = *(const bf16x8*)(Bg + (size_t)col*512 + k0 + (tid&3)*8);
    }
    __syncthreads();
    const short* Ast = (wave < 2) ? Amix : Axt;
    bf16x8 af = *(bf16x8*)(Ast + m*40 + quad*8);
    #pragma unroll
    for (int tc = 0; tc < 4; tc++){
      bf16x8 bf = *(bf16x8*)(Bst + (wave*64 + tc*16 + m)*40 + quad*8);
      acc[tc] = __builtin_amdgcn_mfma_f32_16x16x32_bf16(af, bf, acc[tc], 0, 0, 0);
    }
    __syncthreads();
  }
  // H to LDS
  #pragma unroll
  for (int tc = 0; tc < 4; tc++){
    #pragma unroll
    for (int i = 0; i < 4; i++){
      int col = wave*64 + tc*16 + m;
      Hs[(quad*4 + i)*260 + col] = acc[tc][i];
    }
  }
  __syncthreads();
  // gelu(H + bm1) for cols < 96 (in place)
  for (int i = tid; i < 16*96; i += 256){
    int rr = i / 96, k = i - rr*96;
    Hs[rr*260 + k] = gelu_f(Hs[rr*260 + k] + S[S_BM1 + k]);
  }
  __syncthreads();
  // out = Zres + c + H1 @ Wm2 + bm2   (Wm2 via L1/L2)
  int rr = tid >> 4, pg = tid & 15;
  const float* W2g = S + S_WM2;
  float accv[6] = {};
  for (int k = 0; k < 96; k++){
    float h = Hs[rr*260 + k];
    #pragma unroll
    for (int j = 0; j < 6; j++) accv[j] += h * W2g[k*96 + pg*6 + j];
  }
  int rg = r0 + rr;
  int b2 = rg / DV, d = rg - b2*DV;
  int mode = *flag;
  #pragma unroll
  for (int j = 0; j < 6; j++){
    int p = pg*6 + j;
    float val = Hs[rr*260 + 128 + p] + cb[p] + accv[j] + S[S_BM2 + p];
    size_t oi = ((size_t)b2*96 + p)*DV + d;
    if (mode) ((float*)outv)[oi] = val;
    else ((__hip_bfloat16*)outv)[oi] = __float2bfloat16(val);
  }
}

extern "C" void kernel_launch(void* const* d_in, const int* in_sizes, int n_in,
                              void* d_out, int out_size, void* d_ws, size_t ws_size,
                              hipStream_t stream) {
  float* w = (float*)d_ws;
  float* xt   = w + OFF_XT;
  float* zA   = w + OFF_ZA;
  float* z1   = w + OFF_Z1;
  float* zcp  = w + OFF_ZCP;
  unsigned short* D2h = (unsigned short*)(w + OFF_D2);
  unsigned short* D2l = (unsigned short*)(w + OFF_D2 + 131072);
  unsigned short* D3h = (unsigned short*)(w + OFF_D3);
  float* Tn   = w + OFF_TN;
  float* tb   = w + OFF_TB;
  float* cb   = w + OFF_C;
  float* en   = w + OFF_EN;
  float* nrm  = w + OFF_NORM;
  float* att  = w + OFF_ATT;
  float* dvec = w + OFF_ATT1;
  float* stat = w + OFF_STAT;
  float* abp  = w + OFF_ABP;
  float* abdep= w + OFF_ABDEP;
  int*   flag = (int*)(w + OFF_FLAG);
  float* S    = w + OFF_STG;
  float* tbuf = w + OFF_T;
  float* partP = w + OFF_PARTP;
  float* partD = w + OFF_PARTD;
  float* e_part= w + OFF_EPART;
  float* partM = w + OFF_PARTM;
  unsigned short* BcatTh = (unsigned short*)(w + OFF_BCAT);
  float* PM   = w + OFF_PM;
  float* PC   = w + OFF_PC;

  Ptrs ptrs;
  for (int i = 0; i < 30; i++) ptrs.p[i] = d_in[i];

  k_setup<<<7083, 256, 0, stream>>>(ptrs, w, xt, D2h, D2l, D3h, dvec, PM, PC, Tn, tb);
  k_mega<<<2529, 256, 0, stream>>>(xt, D2h, D2l, zA, e_part, flag, Tn, tb, tbuf, partP, S, PM, PC, cb, BcatTh);
  k_mid1<<<33, 256, 0, stream>>>(e_part, en, nrm, partP, S, abp);
  k_mid2<<<1680, 256, 0, stream>>>(nrm, S, stat, tbuf, zcp, abp, partD);
  k_mid3<<<NROW + NP, 256, 0, stream>>>(zA, nrm, stat, S, partM, partD, abdep);
  k_gemm1<<<dim3(8,84), 256, 0, stream>>>(zA, D3h, z1, partM, xt, S);
  k_z2fatt<<<NROW, 256, 0, stream>>>(zcp, tbuf, abdep, z1, dvec, att);
  k_gemm_out<<<336, 256, 0, stream>>>(z1, zcp, xt, BcatTh, att, cb, S, d_out, flag);
}

// Round 13
// 281.786 us; speedup vs baseline: 1.0326x; 1.0326x over previous
//
#include <hip/hip_runtime.h>
#include <hip/hip_bf16.h>

#define B_    256
#define L_    512
#define DV    21
#define NROW  5376       // B_*DV
#define NP    32
#define PP    16
#define PRED_ 96

// ---------------- workspace layout (float indices) ----------------
static const size_t OFF_XT    = 0;          // 5376x512 f32
static const size_t OFF_ZA    = 2752512;    // zA bf16 (5376x512 ushort)
static const size_t OFF_Z1    = 5505024;    // z1 bf16
static const size_t OFF_ZCP   = 8257536;    // zcp/z2f bf16
static const size_t OFF_D2    = 11010048;   // D2hi bf16 + D2lo bf16
static const size_t OFF_D3    = 11272192;   // D3h bf16
static const size_t OFF_TN    = 11583488;   // 32x16x16
static const size_t OFF_TB    = 11591680;   // 32x16
static const size_t OFF_C     = 11592192;   // 96 (pad 128)
static const size_t OFF_EN    = 11592320;   // 5376
static const size_t OFF_NORM  = 11597696;
static const size_t OFF_ATT   = 11603072;
static const size_t OFF_ATT1  = 11608448;   // dvec (512)
static const size_t OFF_STAT  = 11613824;   // [200],[201]=quantile order stats
static const size_t OFF_ABP   = 11614144;
static const size_t OFF_ABDEP = 11614208;
static const size_t OFF_FLAG  = 11614272;   // int mode flag (1=f32 inputs, 0=bf16)
static const size_t OFF_STG   = 11614336;   // staged f32 weights (854480) -> ends 12468816
static const size_t OFF_T     = 12468816;   // t / z2 bf16
static const size_t OFF_PARTP = 15221328;   // patch stats partials 64x1344
static const size_t OFF_PARTD = 15307344;   // depth stats partials 64x1344
static const size_t OFF_EPART = 15393360;   // energy partials 5376x8
static const size_t OFF_PARTM = 15436368;   // maskgelu BN partials 42x256
static const size_t OFF_BCAT  = 15447120;   // BcatTh bf16 256x512 (65536 floats)
static const size_t OFF_PM    = 15512656;   // foldM partials 8x49152
static const size_t OFF_PC    = 15905872;   // foldC partials 256x96

// staged-weight offsets (relative to OFF_STG)
static const int S_WDCT=0, S_BDCT=24, S_WE=48, S_BE=4144, S_WL=4400, S_BL=790832,
  S_WD=790928, S_BDRES=795024, S_WDC=795040, S_BDC=795552, S_WDC1=795584, S_BDC1=795680,
  S_GD=795712, S_BDN=795736, S_GP=795760, S_BP=795792, S_GDEP=795824, S_BDEP=795856,
  S_THR=795888, S_WM1=795892, S_BM1=845044, S_WM2=845140, S_BM2=854356,
  S_ADWW=854452, S_ADWB=854460, S_ACW=854464, S_ACB=854468, S_AG=854472, S_AB2=854476;

struct Ptrs { const void* p[30]; };

typedef __attribute__((ext_vector_type(8))) short bf16x8;
typedef __attribute__((ext_vector_type(4))) short bf16x4;
typedef __attribute__((ext_vector_type(4))) float f32x4;

__device__ __forceinline__ float bf2f(unsigned short h){
  unsigned u = ((unsigned)h) << 16;
  return __uint_as_float(u);
}
__device__ __forceinline__ short f2b(float f){   // RNE f32 -> bf16
  unsigned u = __float_as_uint(f);
  u = (u + 0x7FFFu + ((u >> 16) & 1u)) >> 16;
  return (short)u;
}
__device__ __forceinline__ float gelu_f(float x){ return 0.5f*x*(1.0f+erff(x*0.70710678118654752440f)); }

#define RD(P,I) (mode ? ((const float*)(P))[(I)] : bf2f(((const unsigned short*)(P))[(I)]))

// ================= setup: stage + transpose + dctmats/dvec + zero + folds (partials) =================
__global__ __launch_bounds__(256) void k_setup(Ptrs ptrs, float* __restrict__ W,
    float* __restrict__ xt, unsigned short* __restrict__ D2h, unsigned short* __restrict__ D2l,
    unsigned short* __restrict__ D3h, float* __restrict__ dvec,
    float* __restrict__ PM, float* __restrict__ PC,
    float* __restrict__ Tn, float* __restrict__ tb){
  int b = blockIdx.x, tid = threadIdx.x;
  int mode = (((const unsigned*)ptrs.p[13])[0] == 0x3F800000u) ? 1 : 0;
  float* S = W + OFF_STG;
  if (b < 3338){
    const int cnt[29] = {21,21,4096,256,786432,96,4096,16,512,32,96,32,21,21,32,32,32,32,1,49152,96,9216,96,5,1,1,1,1,1};
    const int off[29] = {S_WDCT,S_BDCT,S_WE,S_BE,S_WL,S_BL,S_WD,S_BDRES,S_WDC,S_BDC,S_WDC1,S_BDC1,
                         S_GD,S_BDN,S_GP,S_BP,S_GDEP,S_BDEP,S_THR,S_WM1,S_BM1,S_WM2,S_BM2,
                         S_ADWW,S_ADWB,S_ACW,S_ACB,S_AG,S_AB2};
    int gid = b*256 + tid;
    int a = -1, loc = 0, base = 0;
    #pragma unroll
    for (int i = 0; i < 29; i++){
      if (a < 0 && gid < base + cnt[i]){ a = i; loc = gid - base; }
      base += cnt[i];
    }
    if (a < 0) return;
    S[off[a] + loc] = RD(ptrs.p[a+1], loc);
  } else if (b < 4362){
    __shared__ float xs[128*DV];
    int b2 = b - 3338;
    int bb = b2 >> 2, ch = b2 & 3;
    int l0 = ch*128;
    size_t base = (size_t)bb*(L_*DV) + (size_t)l0*DV;
    for (int i = tid; i < 128*DV; i += 256) xs[i] = RD(ptrs.p[0], base + i);
    __syncthreads();
    for (int i = tid; i < 128*DV; i += 256){
      int d = i >> 7, l = i & 127;
      xt[((size_t)bb*DV + d)*512 + l0 + l] = xs[l*DV + d];
    }
  } else if (b < 5386){
    int i = (b - 4362)*256 + tid;
    int kk = i >> 9, m = i & 511;
    const float PIo = 3.14159265358979323846f / 1024.0f;
    int a = ((2*m+1)*kk) & 2047;
    float v = 2.0f * cosf(PIo * (float)a);
    short hi = f2b(v);
    D2h[i] = (unsigned short)hi;
    D2l[i] = (unsigned short)f2b(v - bf2f((unsigned short)hi));
    int a2 = ((2*kk+1)*m) & 2047;
    float w0 = (m==0) ? 0.5f : 1.0f;
    D3h[i] = (unsigned short)f2b(cosf(PIo * (float)a2) * w0 * (1.0f/512.0f));
    if (i < 512){
      const float rs = 22.627416997969522f;
      float s = 0.f;
      #pragma unroll
      for (int k5 = 0; k5 < 5; k5++){
        float awk = RD(ptrs.p[24], k5);
        float sk = ((k5 == 0) ? 0.5f : 0.70710678118654752440f) / rs;
        int a5 = ((2*i+1)*k5) & 2047;
        s += 2.0f * cosf(PIo * (float)a5) * sk * awk;
      }
      dvec[i] = s;
    }
  } else if (b == 5386){
    W[OFF_STAT + tid] = 0.0f;
    if (tid == 0) *(int*)(W + OFF_FLAG) = mode;
  } else if (b < 6923){
    int bb2 = b - 5387;
    int y = bb2 / 192, xb = bb2 - y*192;
    int gid = xb*256 + tid;
    int l = gid/96, p = gid - l*96;
    int n = l>>4, q = l&15;
    int j0 = y*32;
    float acc = 0.f;
    #pragma unroll 8
    for (int j = j0; j < j0+32; j++)
      acc += RD(ptrs.p[3], q*256+j) * RD(ptrs.p[5], (size_t)(n*256+j)*96 + p);
    PM[(size_t)y*49152 + gid] = acc;
  } else if (b < 7051){
    int blkC = b - 6923;
    int rp = tid >> 7, p = tid & 127;
    if (p >= 96) return;
    float acc = 0.f;
    int J0 = blkC*64;
    for (int j = 0; j < 64; j += 2){
      int J = J0 + j + rp;
      acc += RD(ptrs.p[4], J & 255) * RD(ptrs.p[5], (size_t)J*96 + p);
    }
    if (blkC == 0 && rp == 0) acc += RD(ptrs.p[6], p);
    PC[(blkC*2 + rp)*96 + p] = acc;
  } else {
    __shared__ float WeS[4096];
    __shared__ float WdS[4096];
    __shared__ float wdcS[16];
    __shared__ float beS[256];
    __shared__ float bdresS[16];
    int n = b - 7051;
    for (int i = tid; i < 4096; i += 256){ WeS[i] = RD(ptrs.p[3], i); WdS[i] = RD(ptrs.p[7], i); }
    beS[tid] = RD(ptrs.p[4], tid);
    if (tid < 16){ wdcS[tid] = RD(ptrs.p[9], n*16 + tid); bdresS[tid] = RD(ptrs.p[8], tid); }
    __syncthreads();
    int q2 = tid>>4, q = tid&15;
    float R = 0.f;
    for (int j = 0; j < 256; j++) R += WeS[q2*256+j] * WdS[j*16+q];
    float G = 0.f;
    #pragma unroll
    for (int p = 0; p < 16; p++) G += WeS[q2*256 + q*16 + p] * wdcS[p];
    Tn[n*256 + q2*16 + q] = R + G;
    if (tid < 16){
      float rb = bdresS[tid];
      for (int j = 0; j < 256; j++) rb += beS[j] * WdS[j*16+tid];
      float gb = RD(ptrs.p[10], n);
      #pragma unroll
      for (int p = 0; p < 16; p++) gb += beS[tid*16+p] * wdcS[p];
      tb[n*16+tid] = rb + gb;
    }
  }
}

// ================= mega: DCT-GEMM || patch || bcat(+M reduce) || c reduce =================
__global__ __launch_bounds__(256) void k_mega(
    const float* __restrict__ xt, const unsigned short* __restrict__ Bh16,
    const unsigned short* __restrict__ Bl16, unsigned short* __restrict__ Ch,
    float* __restrict__ e_part, const int* __restrict__ flag,
    const float* __restrict__ Tn, const float* __restrict__ tb,
    unsigned short* __restrict__ th, float* __restrict__ partP,
    const float* __restrict__ S, const float* __restrict__ PM,
    const float* __restrict__ PC, float* __restrict__ cb, unsigned short* __restrict__ Bt){
  int b = blockIdx.x, tid = threadIdx.x;
  if (b < 672){
    __shared__ short Ahi[64*40];
    __shared__ short Alo[64*40];
    __shared__ short Bhi[64*40];
    __shared__ short Blo[64*40];
    int mode = *flag;
    int bx = b & 7, by = b >> 3;
    int rowBase = by*64, colBase = bx*64;
    int srow = tid>>2, seg = tid&3;
    int r = rowBase + srow;
    int wave = tid>>6, lane = tid&63;
    int m = lane&15, quad = lane>>4;
    f32x4 acc[4] = {};
    for (int k0 = 0; k0 < 512; k0 += 32){
      float4 a0 = *(const float4*)(xt + (size_t)r*512 + k0 + seg*8);
      float4 a1 = *(const float4*)(xt + (size_t)r*512 + k0 + seg*8 + 4);
      bf16x8 ah;
      float av[8] = {a0.x,a0.y,a0.z,a0.w,a1.x,a1.y,a1.z,a1.w};
      #pragma unroll
      for (int j = 0; j < 8; j++) ah[j] = f2b(av[j]);
      *(bf16x8*)(Ahi + srow*40 + seg*8) = ah;
      if (mode){
        bf16x8 al;
        #pragma unroll
        for (int j = 0; j < 8; j++) al[j] = f2b(av[j] - bf2f((unsigned short)ah[j]));
        *(bf16x8*)(Alo + srow*40 + seg*8) = al;
      }
      *(bf16x8*)(Bhi + srow*40 + seg*8) = *(const bf16x8*)(Bh16 + (size_t)(colBase+srow)*512 + k0 + seg*8);
      *(bf16x8*)(Blo + srow*40 + seg*8) = *(const bf16x8*)(Bl16 + (size_t)(colBase+srow)*512 + k0 + seg*8);
      __syncthreads();
      bf16x8 afh = *(bf16x8*)(Ahi + (wave*16 + m)*40 + quad*8);
      #pragma unroll
      for (int tt = 0; tt < 4; tt++){
        bf16x8 bfh = *(bf16x8*)(Bhi + (tt*16 + m)*40 + quad*8);
        bf16x8 bfl = *(bf16x8*)(Blo + (tt*16 + m)*40 + quad*8);
        acc[tt] = __builtin_amdgcn_mfma_f32_16x16x32_bf16(afh, bfh, acc[tt], 0, 0, 0);
        acc[tt] = __builtin_amdgcn_mfma_f32_16x16x32_bf16(afh, bfl, acc[tt], 0, 0, 0);
      }
      if (mode){
        bf16x8 afl = *(bf16x8*)(Alo + (wave*16 + m)*40 + quad*8);
        #pragma unroll
        for (int tt = 0; tt < 4; tt++){
          bf16x8 bfh = *(bf16x8*)(Bhi + (tt*16 + m)*40 + quad*8);
          bf16x8 bfl = *(bf16x8*)(Blo + (tt*16 + m)*40 + quad*8);
          acc[tt] = __builtin_amdgcn_mfma_f32_16x16x32_bf16(afl, bfh, acc[tt], 0, 0, 0);
          acc[tt] = __builtin_amdgcn_mfma_f32_16x16x32_bf16(afl, bfl, acc[tt], 0, 0, 0);
        }
      }
      __syncthreads();
    }
    float es[4] = {};
    #pragma unroll
    for (int tt = 0; tt < 4; tt++){
      #pragma unroll
      for (int i = 0; i < 4; i++){
        int rr = rowBase + wave*16 + quad*4 + i;
        int cc = colBase + tt*16 + m;
        float v = acc[tt][i];
        Ch[(size_t)rr*512 + cc] = (unsigned short)f2b(v);
        es[i] += v*v;                      // energy from f32 acc (quantile-critical)
      }
    }
    #pragma unroll
    for (int off = 1; off < 16; off <<= 1){
      #pragma unroll
      for (int i = 0; i < 4; i++) es[i] += __shfl_xor(es[i], off);
    }
    if (m == 0){
      #pragma unroll
      for (int i = 0; i < 4; i++){
        int rr = rowBase + wave*16 + quad*4 + i;
        e_part[rr*8 + bx] = es[i];
      }
    }
  } else if (b < 2016){
    int blk = b - 672;
    int n0 = tid >> 4, qq = tid & 15;
    int n1 = n0 + 16;
    float T0[16], T1[16];
    #pragma unroll
    for (int q2 = 0; q2 < 16; q2++){
      T0[q2] = Tn[n0*256 + q2*16 + qq];
      T1[q2] = Tn[n1*256 + q2*16 + qq];
    }
    float tb0 = tb[n0*16 + qq], tb1 = tb[n1*16 + qq];
    float s0 = 0.f, q0 = 0.f, s1 = 0.f, q1 = 0.f;
    #pragma unroll
    for (int rr = 0; rr < 4; rr++){
      int r = blk*4 + rr;
      float x0 = xt[(size_t)r*512 + tid];
      float x1 = xt[(size_t)r*512 + tid + 256];
      float a0 = tb0, a1 = tb1;
      #pragma unroll
      for (int q2 = 0; q2 < 16; q2++){
        a0 += __shfl(x0, q2, 16) * T0[q2];
        a1 += __shfl(x1, q2, 16) * T1[q2];
      }
      th[(size_t)r*512 + tid] = (unsigned short)f2b(a0);       s0 += a0; q0 += a0*a0;
      th[(size_t)r*512 + tid + 256] = (unsigned short)f2b(a1); s1 += a1; q1 += a1*a1;
    }
    #pragma unroll
    for (int off = 1; off < 16; off <<= 1){
      s0 += __shfl_xor(s0, off); q0 += __shfl_xor(q0, off);
      s1 += __shfl_xor(s1, off); q1 += __shfl_xor(q1, off);
    }
    if (qq == 0){
      partP[(2*n0)*1344 + blk] = s0; partP[(2*n0+1)*1344 + blk] = q0;
      partP[(2*n1)*1344 + blk] = s1; partP[(2*n1+1)*1344 + blk] = q1;
    }
  } else if (b < 2528){
    int i = (b - 2016)*256 + tid;
    int cc = i >> 9, mm = i & 511;
    float v = 0.f;
    if (cc < 96) v = S[S_WM1 + mm*96 + cc];
    else if (cc >= 128 && cc < 224){
      int idx = mm*96 + (cc - 128);
      #pragma unroll
      for (int y = 0; y < 8; y++) v += PM[(size_t)y*49152 + idx];
    }
    Bt[i] = (unsigned short)f2b(v);
  } else {
    if (tid < 96){
      float a = 0.f;
      for (int j = 0; j < 256; j++) a += PC[j*96 + tid];
      cb[tid] = a;
    }
  }
}

// ---------------- shared device: BN finalize from partials ----------------
__device__ __forceinline__ void dev_bnfin(const float* part, int P, const float* g,
    const float* bb, float count, float* ab, int c, int tid){
  const float* ps = part + (size_t)(2*c)*P;
  const float* pq = part + (size_t)(2*c+1)*P;
  float s = 0.f, s2 = 0.f;
  for (int i = tid; i < P; i += 256){ s += ps[i]; s2 += pq[i]; }
  for (int off = 32; off; off >>= 1){ s += __shfl_down(s, off); s2 += __shfl_down(s2, off); }
  __shared__ float ws[4][2];
  if ((tid & 63) == 0){ ws[tid>>6][0] = s; ws[tid>>6][1] = s2; }
  __syncthreads();
  if (tid == 0){
    float S1 = ws[0][0]+ws[1][0]+ws[2][0]+ws[3][0];
    float S2 = ws[0][1]+ws[1][1]+ws[2][1]+ws[3][1];
    float mean = S1 / count;
    float var  = S2 / count - mean*mean;
    float al = g[c] * rsqrtf(var + 1e-5f);
    float be = bb[c] - mean * al;
    ab[2*c] = al; ab[2*c+1] = be;
  }
}

// ================= mid1: block0 = energy-reduce + median ; blocks 1..32 = patch BN fin =================
__global__ __launch_bounds__(256) void k_mid1(const float* __restrict__ e_part,
    float* __restrict__ en, float* __restrict__ norm,
    const float* __restrict__ partP, const float* __restrict__ S, float* __restrict__ abp){
  int b = blockIdx.x, tid = threadIdx.x;
  if (b == 0){
    for (int r = tid; r < NROW; r += 256){
      float s = 0.f;
      #pragma unroll
      for (int j = 0; j < 8; j++) s += e_part[r*8 + j];
      en[r] = s;
    }
    __syncthreads();
    int bb = tid;
    float v[DV];
    for (int d = 0; d < DV; d++) v[d] = en[bb*DV + d];
    float med = 0.f;
    for (int i = 0; i < DV; i++){
      int rk = 0;
      for (int j = 0; j < DV; j++) rk += (v[j] < v[i]) || (v[j] == v[i] && j < i);
      if (rk == 10) med = v[i];
    }
    float den = med + 1e-6f;
    for (int d = 0; d < DV; d++) norm[bb*DV + d] = v[d] / den;
  } else {
    dev_bnfin(partP, 1344, S + S_GP, S + S_BP, 86016.0f, abp, b - 1, tid);
  }
}

// ================= mid2: blocks 0..335 = rank ; 336..1679 = z2/conv3 (bf16 t/zcp) =================
__global__ __launch_bounds__(256) void k_mid2(const float* __restrict__ norm,
    const float* __restrict__ S, float* __restrict__ stat,
    unsigned short* __restrict__ th, unsigned short* __restrict__ zch,
    const float* __restrict__ abp, float* __restrict__ partD){
  int b = blockIdx.x, tid = threadIdx.x;
  if (b < 336){
    int cand = tid >> 4, part = tid & 15;
    int idx = b*16 + cand;
    float val = norm[idx];
    int cnt = 0;
    int j0 = part*336;
    for (int j = j0; j < j0 + 336; ++j){
      float v = norm[j];
      cnt += (v < val) || (v == val && j < idx);
    }
    __shared__ int sc[16][17];
    sc[cand][part] = cnt;
    __syncthreads();
    if (part == 0){
      int rank = 0;
      #pragma unroll
      for (int i = 0; i < 16; i++) rank += sc[cand][i];
      float q = S[S_THR];
      float pos = q * 5375.0f;
      int i0 = (int)floorf(pos);
      int i1 = (i0 + 1 > 5375) ? 5375 : i0 + 1;
      if (rank == i0) stat[200] = val;
      if (rank == i1) stat[201] = val;
    }
  } else {
    int blk = b - 336;
    const float* wdc1 = S + S_WDC1;
    const float* bdc1 = S + S_BDC1;
    int n0 = tid >> 4, qq = tid & 15;
    int n1 = n0 + 16;
    float al0 = abp[2*n0], be0 = abp[2*n0+1], al1 = abp[2*n1], be1 = abp[2*n1+1];
    float w00 = wdc1[n0*3], w01 = wdc1[n0*3+1], w02 = wdc1[n0*3+2], bb0 = bdc1[n0];
    float w10 = wdc1[n1*3], w11 = wdc1[n1*3+1], w12 = wdc1[n1*3+2], bb1 = bdc1[n1];
    float s0 = 0.f, q0 = 0.f, s1 = 0.f, q1 = 0.f;
    #pragma unroll
    for (int rr = 0; rr < 4; rr++){
      int r = blk*4 + rr;
      float v0 = bf2f(th[(size_t)r*512 + tid]);
      float v1 = bf2f(th[(size_t)r*512 + tid + 256]);
      float z0  = gelu_f(al0*v0 + be0);
      float z1v = gelu_f(al1*v1 + be1);
      float l0 = __shfl_up(z0, 1, 16);    if (qq == 0)  l0 = 0.f;
      float r0 = __shfl_down(z0, 1, 16);  if (qq == 15) r0 = 0.f;
      float l1 = __shfl_up(z1v, 1, 16);   if (qq == 0)  l1 = 0.f;
      float r1 = __shfl_down(z1v, 1, 16); if (qq == 15) r1 = 0.f;
      float cv0 = w00*l0 + w01*z0  + w02*r0 + bb0;
      float cv1 = w10*l1 + w11*z1v + w12*r1 + bb1;
      zch[(size_t)r*512 + tid] = (unsigned short)f2b(cv0);
      th[(size_t)r*512 + tid]  = (unsigned short)f2b(z0);
      zch[(size_t)r*512 + tid + 256] = (unsigned short)f2b(cv1);
      th[(size_t)r*512 + tid + 256]  = (unsigned short)f2b(z1v);
      s0 += cv0; q0 += cv0*cv0; s1 += cv1; q1 += cv1*cv1;
    }
    #pragma unroll
    for (int off = 1; off < 16; off <<= 1){
      s0 += __shfl_xor(s0, off); q0 += __shfl_xor(q0, off);
      s1 += __shfl_xor(s1, off); q1 += __shfl_xor(q1, off);
    }
    if (qq == 0){
      partD[(2*n0)*1344 + blk] = s0; partD[(2*n0+1)*1344 + blk] = q0;
      partD[(2*n1)*1344 + blk] = s1; partD[(2*n1+1)*1344 + blk] = q1;
    }
  }
}

// ================= mid3: blocks 0..5375 = maskgelu (bf16 zA) ; 5376..5407 = depth BN fin =================
__global__ __launch_bounds__(256) void k_mid3(unsigned short* __restrict__ zAh, const float* __restrict__ norm,
    const float* __restrict__ stat, const float* __restrict__ S,
    float* __restrict__ partM, const float* __restrict__ partD, float* __restrict__ abdep){
  int b = blockIdx.x, tid = threadIdx.x;
  if (b < NROW){
    int r = b;
    int d = r % DV, brow = r / DV;
    float q = S[S_THR];
    float pos = q * 5375.0f; float f = pos - floorf(pos);
    float thr = stat[200] + (stat[201] - stat[200]) * f;
    float mask = norm[r] > thr ? 1.0f : 0.0f;
    float w = S[S_WDCT + d], bb = S[S_BDCT + d];
    float s = 0.f, s2 = 0.f;
    for (int i = tid; i < 512; i += 256){
      float v = bf2f(zAh[(size_t)r*512 + i]) * mask * w + bb;
      float g = gelu_f(v);
      zAh[(size_t)r*512 + i] = (unsigned short)f2b(g);
      s += g; s2 += g*g;
    }
    for (int off = 32; off; off >>= 1){ s += __shfl_down(s, off); s2 += __shfl_down(s2, off); }
    __shared__ float wsum[4][2];
    int wv = tid >> 6;
    if ((tid & 63) == 0){ wsum[wv][0] = s; wsum[wv][1] = s2; }
    __syncthreads();
    if (tid == 0){
      float SS  = wsum[0][0]+wsum[1][0]+wsum[2][0]+wsum[3][0];
      float SS2 = wsum[0][1]+wsum[1][1]+wsum[2][1]+wsum[3][1];
      partM[(2*d)*256 + brow] = SS;
      partM[(2*d+1)*256 + brow] = SS2;
    }
  } else {
    dev_bnfin(partD, 1344, S + S_GDEP, S + S_BDEP, 86016.0f, abdep, b - NROW, tid);
  }
}

// ================= gemm1: idct MFMA GEMM (bf16 A in, bf16 z1 out) with in-block dct-BN finalize =================
__global__ __launch_bounds__(256) void k_gemm1(
    const unsigned short* __restrict__ Ah16, const unsigned short* __restrict__ Bg,
    unsigned short* __restrict__ Ch, const float* __restrict__ partM, const float* __restrict__ xt,
    const float* __restrict__ S){
  __shared__ short Ah[64*40];
  __shared__ short Bh[64*40];
  __shared__ float redS[84];
  __shared__ float abdS[42];
  int tid = threadIdx.x;
  if (tid < 84){
    int s = tid >> 1, h = tid & 1;
    const float* ps = partM + (size_t)s*256 + h*128;
    float a = 0.f;
    #pragma unroll 16
    for (int i = 0; i < 128; i++) a += ps[i];
    redS[tid] = a;
  }
  __syncthreads();
  if (tid < DV){
    float S1 = redS[(2*tid)*2] + redS[(2*tid)*2+1];
    float S2 = redS[(2*tid+1)*2] + redS[(2*tid+1)*2+1];
    float mean = S1 / 131072.0f;
    float var  = S2 / 131072.0f - mean*mean;
    float al = S[S_GD + tid] * rsqrtf(var + 1e-5f);
    abdS[2*tid] = al;
    abdS[2*tid+1] = S[S_BDN + tid] - mean * al;
  }
  __syncthreads();
  int rowBase = blockIdx.y*64, colBase = blockIdx.x*64;
  int srow = tid>>2, seg = tid&3;
  int r = rowBase + srow;
  int d0 = r % DV;
  float alpha = abdS[2*d0], beta = abdS[2*d0+1];
  int wave = tid>>6, lane = tid&63;
  int m = lane&15, quad = lane>>4;
  f32x4 acc[4] = {};
  for (int k0 = 0; k0 < 512; k0 += 32){
    bf16x8 ar = *(const bf16x8*)((const short*)Ah16 + (size_t)r*512 + k0 + seg*8);
    bf16x8 av;
    #pragma unroll
    for (int j = 0; j < 8; j++) av[j] = f2b(alpha*bf2f((unsigned short)ar[j]) + beta);
    *(bf16x8*)(Ah + srow*40 + seg*8) = av;
    bf16x8 bv = *(const bf16x8*)(Bg + (size_t)(colBase+srow)*512 + k0 + seg*8);
    *(bf16x8*)(Bh + srow*40 + seg*8) = bv;
    __syncthreads();
    bf16x8 af = *(bf16x8*)(Ah + (wave*16 + m)*40 + quad*8);
    #pragma unroll
    for (int t = 0; t < 4; t++){
      bf16x8 bf = *(bf16x8*)(Bh + (t*16 + m)*40 + quad*8);
      acc[t] = __builtin_amdgcn_mfma_f32_16x16x32_bf16(af, bf, acc[t], 0, 0, 0);
    }
    __syncthreads();
  }
  #pragma unroll
  for (int t = 0; t < 4; t++){
    #pragma unroll
    for (int i = 0; i < 4; i++){
      int rr = rowBase + wave*16 + quad*4 + i;
      int cc = colBase + t*16 + m;
      int d = rr % DV;
      float v = acc[t][i] + xt[(size_t)rr*512 + cc]*S[S_WDCT + d] + S[S_BDCT + d];
      Ch[(size_t)rr*512 + cc] = (unsigned short)f2b(v);
    }
  }
}

// ================= z2f (in-place over zch) fused with att dot product (all bf16) =================
__global__ __launch_bounds__(256) void k_z2fatt(unsigned short* __restrict__ zch,
    const unsigned short* __restrict__ th, const float* __restrict__ ab,
    const unsigned short* __restrict__ z1h, const float* __restrict__ dvec,
    float* __restrict__ att){
  int r = blockIdx.x, tid = threadIdx.x;
  size_t base = (size_t)r*512;
  float s = 0.f;
  #pragma unroll
  for (int h = 0; h < 2; h++){
    int idx = tid + h*256;
    int n = (idx >> 4) & 31;
    float v = gelu_f(ab[2*n]*bf2f(zch[base+idx]) + ab[2*n+1]) + bf2f(th[base+idx]);
    zch[base+idx] = (unsigned short)f2b(v);
    s += bf2f(z1h[base+idx]) * v * dvec[idx];
  }
  for (int off = 32; off; off >>= 1) s += __shfl_down(s, off);
  __shared__ float ws[4];
  if ((tid & 63) == 0) ws[tid>>6] = s;
  __syncthreads();
  if (tid == 0) att[r] = ws[0]+ws[1]+ws[2]+ws[3];
}

// ================= gemm_out: attfin + MLP/zres GEMM + Wm2 epilogue -> d_out =================
__global__ __launch_bounds__(256) void k_gemm_out(
    const unsigned short* __restrict__ z1h, const unsigned short* __restrict__ zch,
    const float* __restrict__ xt,
    const unsigned short* __restrict__ Bg, const float* __restrict__ att,
    const float* __restrict__ cb, const float* __restrict__ S,
    void* __restrict__ outv, const int* __restrict__ flag){
  __shared__ short Amix[16*40];
  __shared__ short Axt[16*40];
  __shared__ short Bst[256*40];
  __shared__ float Hs[16*260];
  __shared__ float att1S[16];
  __shared__ float asum[2];
  __shared__ float ws[4][2];
  int bb = blockIdx.x, tid = threadIdx.x;
  int r0 = bb*16;
  {
    float s = 0.f, s2 = 0.f;
    for (int i = tid; i < NROW; i += 256){ float a = att[i]; s += a; s2 += a*a; }
    for (int off = 32; off; off >>= 1){ s += __shfl_down(s, off); s2 += __shfl_down(s2, off); }
    if ((tid & 63) == 0){ ws[tid>>6][0] = s; ws[tid>>6][1] = s2; }
    __syncthreads();
    if (tid == 0){
      asum[0] = ws[0][0]+ws[1][0]+ws[2][0]+ws[3][0];
      asum[1] = ws[0][1]+ws[1][1]+ws[2][1]+ws[3][1];
    }
    __syncthreads();
  }
  if (tid < 16){
    int r = r0 + tid; int b2 = r / DV, d = r - b2*DV;
    float mean = asum[0] / 5376.0f;
    float var  = asum[1] / 5376.0f - mean*mean;
    float al = S[S_AG] * rsqrtf(var + 1e-5f);
    float bbx = S[S_AB2];
    float cw = S[S_ACW], cb2 = S[S_ACB];
    float v[DV]; float mx = -1e30f;
    for (int dd = 0; dd < DV; dd++){
      float a = att[b2*DV + dd];
      a = gelu_f(al*(a - mean) + bbx);
      a = a*cw + cb2;
      v[dd] = a; mx = fmaxf(mx, a);
    }
    float ss = 0.f;
    for (int dd = 0; dd < DV; dd++) ss += expf(v[dd] - mx);
    att1S[tid] = expf(v[d] - mx) / ss;
  }
  __syncthreads();
  int wave = tid>>6, lane = tid&63;
  int m = lane&15, quad = lane>>4;
  f32x4 acc[4] = {};
  for (int k0 = 0; k0 < 512; k0 += 32){
    if (tid < 128){
      int srow = tid >> 3, seg = tid & 7;
      int r = r0 + srow;
      float a1r = att1S[srow];
      float om = 1.0f - a1r;
      bf16x4 zf = *(const bf16x4*)((const short*)z1h + (size_t)r*512 + k0 + seg*4);
      bf16x4 cf = *(const bf16x4*)((const short*)zch + (size_t)r*512 + k0 + seg*4);
      bf16x4 mv;
      #pragma unroll
      for (int j = 0; j < 4; j++)
        mv[j] = f2b(a1r*bf2f((unsigned short)zf[j]) + om*bf2f((unsigned short)cf[j]));
      *(bf16x4*)(Amix + srow*40 + seg*4) = mv;
      float4 xf = *(const float4*)(xt + (size_t)r*512 + k0 + seg*4);
      bf16x4 xv;
      xv[0] = f2b(xf.x); xv[1] = f2b(xf.y); xv[2] = f2b(xf.z); xv[3] = f2b(xf.w);
      *(bf16x4*)(Axt + srow*40 + seg*4) = xv;
    }
    #pragma unroll
    for (int cg = 0; cg < 4; cg++){
      int col = cg*64 + (tid>>2);
      *(bf16x8*)(Bst + col*40 + (tid&3)*8) = *(const bf16x8*)(Bg + (size_t)col*512 + k0 + (tid&3)*8);
    }
    __syncthreads();
    const short* Ast = (wave < 2) ? Amix : Axt;
    bf16x8 af = *(bf16x8*)(Ast + m*40 + quad*8);
    #pragma unroll
    for (int tc = 0; tc < 4; tc++){
      bf16x8 bf = *(bf16x8*)(Bst + (wave*64 + tc*16 + m)*40 + quad*8);
      acc[tc] = __builtin_amdgcn_mfma_f32_16x16x32_bf16(af, bf, acc[tc], 0, 0, 0);
    }
    __syncthreads();
  }
  #pragma unroll
  for (int tc = 0; tc < 4; tc++){
    #pragma unroll
    for (int i = 0; i < 4; i++){
      int col = wave*64 + tc*16 + m;
      Hs[(quad*4 + i)*260 + col] = acc[tc][i];
    }
  }
  __syncthreads();
  for (int i = tid; i < 16*96; i += 256){
    int rr = i / 96, k = i - rr*96;
    Hs[rr*260 + k] = gelu_f(Hs[rr*260 + k] + S[S_BM1 + k]);
  }
  __syncthreads();
  int rr = tid >> 4, pg = tid & 15;
  const float* W2g = S + S_WM2;
  float accv[6] = {};
  for (int k = 0; k < 96; k++){
    float h = Hs[rr*260 + k];
    #pragma unroll
    for (int j = 0; j < 6; j++) accv[j] += h * W2g[k*96 + pg*6 + j];
  }
  int rg = r0 + rr;
  int b2 = rg / DV, d = rg - b2*DV;
  int mode = *flag;
  #pragma unroll
  for (int j = 0; j < 6; j++){
    int p = pg*6 + j;
    float val = Hs[rr*260 + 128 + p] + cb[p] + accv[j] + S[S_BM2 + p];
    size_t oi = ((size_t)b2*96 + p)*DV + d;
    if (mode) ((float*)outv)[oi] = val;
    else ((__hip_bfloat16*)outv)[oi] = __float2bfloat16(val);
  }
}

extern "C" void kernel_launch(void* const* d_in, const int* in_sizes, int n_in,
                              void* d_out, int out_size, void* d_ws, size_t ws_size,
                              hipStream_t stream) {
  float* w = (float*)d_ws;
  float* xt   = w + OFF_XT;
  unsigned short* zAh = (unsigned short*)(w + OFF_ZA);
  unsigned short* z1h = (unsigned short*)(w + OFF_Z1);
  unsigned short* zch = (unsigned short*)(w + OFF_ZCP);
  unsigned short* D2h = (unsigned short*)(w + OFF_D2);
  unsigned short* D2l = (unsigned short*)(w + OFF_D2 + 131072);
  unsigned short* D3h = (unsigned short*)(w + OFF_D3);
  float* Tn   = w + OFF_TN;
  float* tb   = w + OFF_TB;
  float* cb   = w + OFF_C;
  float* en   = w + OFF_EN;
  float* nrm  = w + OFF_NORM;
  float* att  = w + OFF_ATT;
  float* dvec = w + OFF_ATT1;
  float* stat = w + OFF_STAT;
  float* abp  = w + OFF_ABP;
  float* abdep= w + OFF_ABDEP;
  int*   flag = (int*)(w + OFF_FLAG);
  float* S    = w + OFF_STG;
  unsigned short* th = (unsigned short*)(w + OFF_T);
  float* partP = w + OFF_PARTP;
  float* partD = w + OFF_PARTD;
  float* e_part= w + OFF_EPART;
  float* partM = w + OFF_PARTM;
  unsigned short* BcatTh = (unsigned short*)(w + OFF_BCAT);
  float* PM   = w + OFF_PM;
  float* PC   = w + OFF_PC;

  Ptrs ptrs;
  for (int i = 0; i < 30; i++) ptrs.p[i] = d_in[i];

  k_setup<<<7083, 256, 0, stream>>>(ptrs, w, xt, D2h, D2l, D3h, dvec, PM, PC, Tn, tb);
  k_mega<<<2529, 256, 0, stream>>>(xt, D2h, D2l, zAh, e_part, flag, Tn, tb, th, partP, S, PM, PC, cb, BcatTh);
  k_mid1<<<33, 256, 0, stream>>>(e_part, en, nrm, partP, S, abp);
  k_mid2<<<1680, 256, 0, stream>>>(nrm, S, stat, th, zch, abp, partD);
  k_mid3<<<NROW + NP, 256, 0, stream>>>(zAh, nrm, stat, S, partM, partD, abdep);
  k_gemm1<<<dim3(8,84), 256, 0, stream>>>(zAh, D3h, z1h, partM, xt, S);
  k_z2fatt<<<NROW, 256, 0, stream>>>(zch, th, abdep, z1h, dvec, att);
  k_gemm_out<<<336, 256, 0, stream>>>(z1h, zch, xt, BcatTh, att, cb, S, d_out, flag);
}